// Round 3
// baseline (1270.203 us; speedup 1.0000x reference)
//
#include <hip/hip_runtime.h>

typedef unsigned short u16;
typedef unsigned int   u32;

#define S_LEN 2048
#define SCALE 0.08838834764831845f
#define NEGBIG (-1e30f)

__device__ __forceinline__ float bf2f(u16 u) {
  union { u32 i; float f; } v; v.i = ((u32)u) << 16; return v.f;
}
__device__ __forceinline__ u16 f2b(float f) {
  union { float f; u32 i; } v; v.f = f;
  u32 x = v.i;
  u32 r = x + 0x7fffu + ((x >> 16) & 1u);
  return (u16)(r >> 16);
}
__device__ __forceinline__ float2 bfpair(u32 u) {
  union { u32 i; float f; } lo, hi;
  lo.i = u << 16; hi.i = u & 0xffff0000u;
  float2 r; r.x = lo.f; r.y = hi.f; return r;
}
__device__ __forceinline__ u32 pack2(float a, float b) {
  return (u32)f2b(a) | ((u32)f2b(b) << 16);
}

// load 16 consecutive elements, convert to bf16 u16
__device__ __forceinline__ void load16(const float* p, u16* dst) {
  #pragma unroll
  for (int i = 0; i < 16; i += 4) {
    float4 v = *(const float4*)(p + i);
    dst[i]     = f2b(v.x); dst[i + 1] = f2b(v.y);
    dst[i + 2] = f2b(v.z); dst[i + 3] = f2b(v.w);
  }
}
__device__ __forceinline__ void load16(const u16* p, u16* dst) {
  uint4 v0 = *(const uint4*)p, v1 = *(const uint4*)(p + 8);
  *(uint4*)dst = v0; *(uint4*)(dst + 8) = v1;
}

// store 4 consecutive outputs (bf16 or f32)
__device__ __forceinline__ void store4(u16* o, float a, float b, float c, float d) {
  uint2 pk; pk.x = pack2(a, b); pk.y = pack2(c, d);
  *(uint2*)o = pk;
}
__device__ __forceinline__ void store4(float* o, float a, float b, float c, float d) {
  float4 v; v.x = a; v.y = b; v.z = c; v.w = d;
  *(float4*)o = v;
}

// ---------------------------------------------------------------------------
// 64x64-tile GEMM: C[M,N] = A[M,K] * W[K,N], fp32 accumulate.
// TA/TW = float (f32 input) or u16 (bf16 ws intermediate); TO = u16 or float.
// Column ranges route to up to 3 weight/output pairs (fused Q|K|V).
// ---------------------------------------------------------------------------
template <typename TA, typename TW, typename TO>
__global__ __launch_bounds__(256) void gemm64(
    const TA* __restrict__ A, int lda, int Kdim,
    const TW* __restrict__ W0, int ldw0, TO* __restrict__ O0, int ldo0,
    const TW* __restrict__ W1, int ldw1, TO* __restrict__ O1, int ldo1,
    const TW* __restrict__ W2, int ldw2, TO* __restrict__ O2, int ldo2,
    int c1, int c2)
{
  const int n0 = blockIdx.x * 64;
  const int m0 = blockIdx.y * 64;
  const TW* W; TO* O; int ldw, ldo, col;
  if (n0 < c1)      { W = W0; O = O0; ldw = ldw0; ldo = ldo0; col = n0; }
  else if (n0 < c2) { W = W1; O = O1; ldw = ldw1; ldo = ldo1; col = n0 - c1; }
  else              { W = W2; O = O2; ldw = ldw2; ldo = ldo2; col = n0 - c2; }

  __shared__ __align__(16) u16 At[64][72];  // [k][m] (A transposed)
  __shared__ __align__(16) u16 Bs[64][72];  // [k][n]

  const int t  = threadIdx.x;
  const int tx = t & 15, ty = t >> 4;
  const int sm = t >> 2;            // staging row 0..63
  const int sc = (t & 3) * 16;      // staging col {0,16,32,48}

  float acc[4][4];
  #pragma unroll
  for (int i = 0; i < 4; ++i)
    #pragma unroll
    for (int j = 0; j < 4; ++j) acc[i][j] = 0.f;

  for (int k0 = 0; k0 < Kdim; k0 += 64) {
    __syncthreads();
    {
      u16 tmp[16];
      load16(A + (size_t)(m0 + sm) * lda + k0 + sc, tmp);
      #pragma unroll
      for (int j = 0; j < 16; ++j) At[sc + j][sm] = tmp[j];
    }
    load16(W + (size_t)(k0 + sm) * ldw + col + sc, &Bs[sm][sc]);
    __syncthreads();
    #pragma unroll 8
    for (int kk = 0; kk < 64; ++kk) {
      uint2 au = *(const uint2*)&At[kk][ty * 4];
      uint2 bu = *(const uint2*)&Bs[kk][tx * 4];
      float2 a01 = bfpair(au.x), a23 = bfpair(au.y);
      float2 b01 = bfpair(bu.x), b23 = bfpair(bu.y);
      float av[4] = {a01.x, a01.y, a23.x, a23.y};
      float bv[4] = {b01.x, b01.y, b23.x, b23.y};
      #pragma unroll
      for (int i = 0; i < 4; ++i)
        #pragma unroll
        for (int j = 0; j < 4; ++j) acc[i][j] += av[i] * bv[j];
    }
  }
  #pragma unroll
  for (int i = 0; i < 4; ++i) {
    TO* o = O + (size_t)(m0 + ty * 4 + i) * ldo + col + tx * 4;
    store4(o, acc[i][0], acc[i][1], acc[i][2], acc[i][3]);
  }
}

// ---------------------------------------------------------------------------
// RoPE applied in place to Q [4096,8,128] and K [4096,4,128] (bf16 ws).
// cos/sin tables are f32 inputs.
// ---------------------------------------------------------------------------
__global__ __launch_bounds__(256) void rope_kernel(u16* __restrict__ Qb, u16* __restrict__ Kb,
                                                   const float* __restrict__ cb, const float* __restrict__ sb)
{
  int idx = blockIdx.x * 256 + threadIdx.x;       // B*S*(8+4)*64 total
  int d    = idx & 63;
  int head = (idx >> 6) % 12;
  int pos  = idx / (64 * 12);                     // b*S + s
  int s    = pos & (S_LEN - 1);
  float c0 = cb[s * 128 + d];
  float s0 = sb[s * 128 + d];
  float c1 = cb[s * 128 + d + 64];
  float s1 = sb[s * 128 + d + 64];
  u16* base = (head < 8) ? (Qb + (size_t)pos * 1024 + head * 128)
                         : (Kb + (size_t)pos * 512 + (head - 8) * 128);
  float x0 = bf2f(base[d]), x1 = bf2f(base[d + 64]);
  base[d]      = f2b(x0 * c0 - x1 * s0);
  base[d + 64] = f2b(x1 * c1 + x0 * s1);
}

// ---------------------------------------------------------------------------
// dyn[b,s,h] = exp(A[h] * softplus(v_flat[b,s,:] @ Wdt[:,h])); one wave/(b,s)
// Vb is bf16 ws; Wdt/A are f32 inputs.
// ---------------------------------------------------------------------------
__global__ __launch_bounds__(64) void dyn_kernel(const u16* __restrict__ Vb, const float* __restrict__ Wdt,
                                                 const float* __restrict__ Af, float* __restrict__ dynb)
{
  int pos  = blockIdx.x;      // 0..4095
  int lane = threadIdx.x;
  float acc[8];
  #pragma unroll
  for (int h = 0; h < 8; ++h) acc[h] = 0.f;
  for (int j = lane; j < 512; j += 64) {
    float v = bf2f(Vb[(size_t)pos * 512 + j]);
    float4 w0 = *(const float4*)(Wdt + j * 8);
    float4 w1 = *(const float4*)(Wdt + j * 8 + 4);
    acc[0] += v * w0.x; acc[1] += v * w0.y; acc[2] += v * w0.z; acc[3] += v * w0.w;
    acc[4] += v * w1.x; acc[5] += v * w1.y; acc[6] += v * w1.z; acc[7] += v * w1.w;
  }
  #pragma unroll
  for (int off = 32; off > 0; off >>= 1)
    #pragma unroll
    for (int h = 0; h < 8; ++h) acc[h] += __shfl_down(acc[h], off, 64);
  if (lane == 0) {
    #pragma unroll
    for (int h = 0; h < 8; ++h) {
      float dt = acc[h];
      float sp = (dt > 20.f) ? dt : log1pf(__expf(dt));
      dynb[(size_t)pos * 8 + h] = __expf(Af[h] * sp);
    }
  }
}

// ---------------------------------------------------------------------------
// Flash-style causal attention with per-key bias dyn[b,k,h]. One block per
// (b, h, 64-q tile); 64-key tiles; K and V share one LDS buffer.
// ctx aliases Qb: each block reads its Q tile to LDS first, writes the same
// region at the end; regions across blocks are disjoint.
// ---------------------------------------------------------------------------
__global__ __launch_bounds__(256) void attn_kernel(const u16* __restrict__ Qb, const u16* __restrict__ Kb,
                                                   const u16* __restrict__ Vb, const float* __restrict__ dynb,
                                                   u16* __restrict__ ctx)
{
  const int qblk = (int)gridDim.x - 1 - (int)blockIdx.x;  // heavy blocks first
  const int h   = blockIdx.y;
  const int b   = blockIdx.z;
  const int kvh = h >> 1;                                  // GQA: GROUPS=2
  const int q0  = qblk * 64;

  __shared__ __align__(16) u16 Qs[64][136];
  __shared__ __align__(16) u16 KVs[64][136];
  __shared__ float Wsm[64][65];
  __shared__ float mS[64], lS[64], aS[64], dynS[64];

  const int t  = threadIdx.x;
  const int tx = t & 15, ty = t >> 4;         // score-phase mapping
  const int pq = t & 63, pd = (t >> 6) * 32;  // PV-phase mapping
  const int lr = t & 63, lc = (t >> 6) * 32;  // staging mapping

  {
    const uint4* src = (const uint4*)(Qb + (size_t)(b * S_LEN + q0 + lr) * 1024 + h * 128 + lc);
    uint4* dst = (uint4*)&Qs[lr][lc];
    dst[0] = src[0]; dst[1] = src[1]; dst[2] = src[2]; dst[3] = src[3];
  }
  if (t < 64) { mS[t] = NEGBIG; lS[t] = 0.f; }

  float O[32];
  #pragma unroll
  for (int i = 0; i < 32; ++i) O[i] = 0.f;

  for (int kt = 0; kt <= qblk; ++kt) {
    const int k0 = kt * 64;
    __syncthreads();  // prior PV reads of KVs/Wsm done
    {
      const uint4* src = (const uint4*)(Kb + (size_t)(b * S_LEN + k0 + lr) * 512 + kvh * 128 + lc);
      uint4* dst = (uint4*)&KVs[lr][lc];
      dst[0] = src[0]; dst[1] = src[1]; dst[2] = src[2]; dst[3] = src[3];
    }
    if (t < 64) dynS[t] = dynb[(size_t)(b * S_LEN + k0 + t) * 8 + h];
    __syncthreads();

    // ---- scores: sc[qi][ki] = Q[q0+ty*4+qi] . K[k0+tx*4+ki] ----
    float sc[4][4];
    #pragma unroll
    for (int i = 0; i < 4; ++i)
      #pragma unroll
      for (int j = 0; j < 4; ++j) sc[i][j] = 0.f;

    for (int d = 0; d < 128; d += 8) {
      float qv[4][8], kf[4][8];
      #pragma unroll
      for (int qi = 0; qi < 4; ++qi) {
        uint4 r = *(const uint4*)&Qs[ty * 4 + qi][d];
        u32 u[4] = {r.x, r.y, r.z, r.w};
        #pragma unroll
        for (int j = 0; j < 4; ++j) { float2 p = bfpair(u[j]); qv[qi][2*j] = p.x; qv[qi][2*j+1] = p.y; }
      }
      #pragma unroll
      for (int ki = 0; ki < 4; ++ki) {
        uint4 r = *(const uint4*)&KVs[tx * 4 + ki][d];
        u32 u[4] = {r.x, r.y, r.z, r.w};
        #pragma unroll
        for (int j = 0; j < 4; ++j) { float2 p = bfpair(u[j]); kf[ki][2*j] = p.x; kf[ki][2*j+1] = p.y; }
      }
      #pragma unroll
      for (int qi = 0; qi < 4; ++qi)
        #pragma unroll
        for (int ki = 0; ki < 4; ++ki)
          #pragma unroll
          for (int j = 0; j < 8; ++j) sc[qi][ki] += qv[qi][j] * kf[ki][j];
    }

    // ---- online softmax (rows owned by one 16-lane tx-group each) ----
    #pragma unroll
    for (int qi = 0; qi < 4; ++qi) {
      const int lq = ty * 4 + qi;
      const int q  = q0 + lq;
      float mx = NEGBIG;
      #pragma unroll
      for (int ki = 0; ki < 4; ++ki) {
        const int k = k0 + tx * 4 + ki;
        float v = sc[qi][ki] * SCALE + dynS[tx * 4 + ki];
        if (k > q) v = NEGBIG;
        sc[qi][ki] = v;
        mx = fmaxf(mx, v);
      }
      #pragma unroll
      for (int off = 1; off < 16; off <<= 1) mx = fmaxf(mx, __shfl_xor(mx, off, 64));
      const float mold = mS[lq];
      const float mn = fmaxf(mold, mx);
      float sum = 0.f;
      #pragma unroll
      for (int ki = 0; ki < 4; ++ki) {
        float p = __expf(sc[qi][ki] - mn);   // masked -> exp(-huge)=0
        Wsm[lq][tx * 4 + ki] = p;
        sum += p;
      }
      #pragma unroll
      for (int off = 1; off < 16; off <<= 1) sum += __shfl_xor(sum, off, 64);
      if (tx == 0) {
        const float al = __expf(mold - mn);  // first tile: exp(-huge)=0
        aS[lq] = al;
        mS[lq] = mn;
        lS[lq] = lS[lq] * al + sum;
      }
    }
    __syncthreads();  // Wsm/aS ready, KVs score reads done

    // ---- load V into the shared K/V buffer ----
    {
      const uint4* src = (const uint4*)(Vb + (size_t)(b * S_LEN + k0 + lr) * 512 + kvh * 128 + lc);
      uint4* dst = (uint4*)&KVs[lr][lc];
      dst[0] = src[0]; dst[1] = src[1]; dst[2] = src[2]; dst[3] = src[3];
    }
    __syncthreads();

    // ---- PV: thread owns (q=pq, d=pd..pd+31) ----
    const float al = aS[pq];
    #pragma unroll
    for (int i = 0; i < 32; ++i) O[i] *= al;
    #pragma unroll 2
    for (int kk = 0; kk < 64; ++kk) {
      const float w = Wsm[pq][kk];
      uint4 r0 = *(const uint4*)&KVs[kk][pd];
      uint4 r1 = *(const uint4*)&KVs[kk][pd + 8];
      uint4 r2 = *(const uint4*)&KVs[kk][pd + 16];
      uint4 r3 = *(const uint4*)&KVs[kk][pd + 24];
      u32 u[16] = {r0.x,r0.y,r0.z,r0.w, r1.x,r1.y,r1.z,r1.w,
                   r2.x,r2.y,r2.z,r2.w, r3.x,r3.y,r3.z,r3.w};
      #pragma unroll
      for (int p = 0; p < 16; ++p) {
        float2 vv = bfpair(u[p]);
        O[2*p]     += w * vv.x;
        O[2*p + 1] += w * vv.y;
      }
    }
  }

  const float linv = 1.f / lS[pq];
  u16* o = ctx + (size_t)(b * S_LEN + q0 + pq) * 1024 + h * 128 + pd;
  #pragma unroll
  for (int p = 0; p < 4; ++p) {
    uint4 pk;
    pk.x = pack2(O[8*p+0] * linv, O[8*p+1] * linv);
    pk.y = pack2(O[8*p+2] * linv, O[8*p+3] * linv);
    pk.z = pack2(O[8*p+4] * linv, O[8*p+5] * linv);
    pk.w = pack2(O[8*p+6] * linv, O[8*p+7] * linv);
    *(uint4*)(o + 8*p) = pk;
  }
}

// ---------------------------------------------------------------------------
extern "C" void kernel_launch(void* const* d_in, const int* in_sizes, int n_in,
                              void* d_out, int out_size, void* d_ws, size_t ws_size,
                              hipStream_t stream)
{
  // Inputs are float32 (reference dtypes); OUTPUT IS FLOAT32 (reference
  // returns f32 — the "bf16" in the harness error label is hard-coded).
  const float* hidden = (const float*)d_in[0];
  const float* Wq     = (const float*)d_in[1];
  const float* Wk     = (const float*)d_in[2];
  const float* Wv     = (const float*)d_in[3];
  const float* Wdt    = (const float*)d_in[4];
  const float* Af     = (const float*)d_in[5];
  const float* Wo     = (const float*)d_in[6];
  const float* cosb   = (const float*)d_in[7];
  const float* sinb   = (const float*)d_in[8];
  // d_in[9] = causal mask, structurally k>q — not read.
  float* out = (float*)d_out;

  // ws: Qb doubles as ctx (attn writes its own q-tile region after reading it)
  u16* Qb  = (u16*)d_ws;                       // [4096,1024] bf16  (later: ctx)
  u16* Kb  = Qb + (size_t)4096 * 1024;         // [4096, 512] bf16
  u16* Vb  = Kb + (size_t)4096 * 512;          // [4096, 512] bf16
  float* dynb = (float*)(Vb + (size_t)4096 * 512);    // [4096,8] f32
  u16* ctx = Qb;

  // fused QKV projection: N = 1024 | 512 | 512, bf16 outputs to ws
  gemm64<float, float, u16><<<dim3(32, 64), 256, 0, stream>>>(hidden, 1024, 1024,
      Wq, 1024, Qb, 1024,
      Wk,  512, Kb,  512,
      Wv,  512, Vb,  512,
      1024, 1536);
  rope_kernel<<<12288, 256, 0, stream>>>(Qb, Kb, cosb, sinb);
  dyn_kernel<<<4096, 64, 0, stream>>>(Vb, Wdt, Af, dynb);
  attn_kernel<<<dim3(32, 8, 2), 256, 0, stream>>>(Qb, Kb, Vb, dynb, ctx);
  // output projection -> d_out (f32)
  gemm64<u16, float, float><<<dim3(16, 64), 256, 0, stream>>>(ctx, 1024, 1024,
      Wo, 1024, out, 1024,
      Wo, 1024, out, 1024,
      Wo, 1024, out, 1024,
      1 << 30, 1 << 30);
}

// Round 4
// 545.227 us; speedup vs baseline: 2.3297x; 2.3297x over previous
//
#include <hip/hip_runtime.h>

typedef unsigned short u16;
typedef unsigned int   u32;
typedef __bf16 bf16;
typedef bf16  bf16x8 __attribute__((ext_vector_type(8)));
typedef float f32x4  __attribute__((ext_vector_type(4)));

#define S_LEN 2048
#define SCALE 0.08838834764831845f
#define NEGBIG (-1e30f)

__device__ __forceinline__ float bf2f(u16 u) {
  union { u32 i; float f; } v; v.i = ((u32)u) << 16; return v.f;
}
__device__ __forceinline__ u16 f2b(float f) {
  union { float f; u32 i; } v; v.f = f;
  u32 x = v.i;
  u32 r = x + 0x7fffu + ((x >> 16) & 1u);
  return (u16)(r >> 16);
}

// load 16 consecutive elements as bf16 u16 (convert when f32 source)
__device__ __forceinline__ void load16(const float* p, u16* dst) {
  #pragma unroll
  for (int i = 0; i < 16; i += 4) {
    float4 v = *(const float4*)(p + i);
    dst[i]     = f2b(v.x); dst[i + 1] = f2b(v.y);
    dst[i + 2] = f2b(v.z); dst[i + 3] = f2b(v.w);
  }
}
__device__ __forceinline__ void load16(const u16* p, u16* dst) {
  uint4 v0 = *(const uint4*)p, v1 = *(const uint4*)(p + 8);
  *(uint4*)dst = v0; *(uint4*)(dst + 8) = v1;
}

__device__ __forceinline__ void storeo(float* p, float v) { *p = v; }
__device__ __forceinline__ void storeo(u16* p, float v)   { *p = f2b(v); }

__device__ __forceinline__ bf16x8 frag8(const u16* p) {
  union { uint4 u; bf16x8 v; } c;
  c.u = *(const uint4*)p;
  return c.v;
}
__device__ __forceinline__ f32x4 zero4() {
  f32x4 z = {0.f, 0.f, 0.f, 0.f}; return z;
}

// ---------------------------------------------------------------------------
// MFMA GEMM: C[M,N] = A[M,K] * W[K,N]. A f32-or-bf16, W f32 (converted during
// staging), out f32-or-bf16. 64x64 tile, 4 waves x (16m x 64n), BK=64.
// Column routing gives fused Q|K|V in one launch.
// ---------------------------------------------------------------------------
template <typename TA, typename TO>
__global__ __launch_bounds__(256) void gemm_mfma(
    const TA* __restrict__ A, int lda, int Kdim,
    const float* __restrict__ W0, int ldw0, TO* __restrict__ O0, int ldo0,
    const float* __restrict__ W1, int ldw1, TO* __restrict__ O1, int ldo1,
    const float* __restrict__ W2, int ldw2, TO* __restrict__ O2, int ldo2,
    int c1, int c2)
{
  const int n0 = blockIdx.x * 64;
  const int m0 = blockIdx.y * 64;
  const float* W; TO* O; int ldw, ldo, col;
  if (n0 < c1)      { W = W0; O = O0; ldw = ldw0; ldo = ldo0; col = n0; }
  else if (n0 < c2) { W = W1; O = O1; ldw = ldw1; ldo = ldo1; col = n0 - c1; }
  else              { W = W2; O = O2; ldw = ldw2; ldo = ldo2; col = n0 - c2; }

  __shared__ __align__(16) u16 As[64][72];   // [m][k]
  __shared__ __align__(16) u16 Bs[64][72];   // [n][k]  (W transposed)

  const int t    = threadIdx.x;
  const int w    = t >> 6, lane = t & 63, quad = lane >> 4, l16 = lane & 15;
  const int sr   = t >> 2, scc = (t & 3) * 16;

  f32x4 acc[4];
  #pragma unroll
  for (int nt = 0; nt < 4; ++nt) acc[nt] = zero4();

  for (int k0 = 0; k0 < Kdim; k0 += 64) {
    __syncthreads();
    {  // A tile: row sr (m), cols scc..scc+15 (k)
      u16 tmp[16];
      load16(A + (size_t)(m0 + sr) * lda + k0 + scc, tmp);
      *(uint4*)&As[sr][scc]     = *(uint4*)tmp;
      *(uint4*)&As[sr][scc + 8] = *(uint4*)(tmp + 8);
    }
    {  // W tile transposed: read W[k0+sr][col+scc..+15] (coalesced), scatter to Bs[n][k]
      const float* wp = W + (size_t)(k0 + sr) * ldw + col + scc;
      #pragma unroll
      for (int i = 0; i < 16; i += 4) {
        float4 v = *(const float4*)(wp + i);
        Bs[scc + i][sr]     = f2b(v.x);
        Bs[scc + i + 1][sr] = f2b(v.y);
        Bs[scc + i + 2][sr] = f2b(v.z);
        Bs[scc + i + 3][sr] = f2b(v.w);
      }
    }
    __syncthreads();
    #pragma unroll
    for (int ks = 0; ks < 2; ++ks) {
      bf16x8 a = frag8(&As[w * 16 + l16][ks * 32 + quad * 8]);
      #pragma unroll
      for (int nt = 0; nt < 4; ++nt) {
        bf16x8 bw = frag8(&Bs[nt * 16 + l16][ks * 32 + quad * 8]);
        acc[nt] = __builtin_amdgcn_mfma_f32_16x16x32_bf16(a, bw, acc[nt], 0, 0, 0);
      }
    }
  }
  #pragma unroll
  for (int nt = 0; nt < 4; ++nt)
    #pragma unroll
    for (int r = 0; r < 4; ++r) {
      const int m = m0 + w * 16 + quad * 4 + r;
      const int n = col + nt * 16 + l16;
      storeo(O + (size_t)m * ldo + n, acc[nt][r]);
    }
}

// ---------------------------------------------------------------------------
// RoPE in place on Q [4096,8,128] and K [4096,4,128] (bf16 ws).
// ---------------------------------------------------------------------------
__global__ __launch_bounds__(256) void rope_kernel(u16* __restrict__ Qb, u16* __restrict__ Kb,
                                                   const float* __restrict__ cb, const float* __restrict__ sb)
{
  int idx = blockIdx.x * 256 + threadIdx.x;
  int d    = idx & 63;
  int head = (idx >> 6) % 12;
  int pos  = idx / (64 * 12);
  int s    = pos & (S_LEN - 1);
  float c0 = cb[s * 128 + d];
  float s0 = sb[s * 128 + d];
  float c1 = cb[s * 128 + d + 64];
  float s1 = sb[s * 128 + d + 64];
  u16* base = (head < 8) ? (Qb + (size_t)pos * 1024 + head * 128)
                         : (Kb + (size_t)pos * 512 + (head - 8) * 128);
  float x0 = bf2f(base[d]), x1 = bf2f(base[d + 64]);
  base[d]      = f2b(x0 * c0 - x1 * s0);
  base[d + 64] = f2b(x1 * c1 + x0 * s1);
}

// ---------------------------------------------------------------------------
// dyn[b,s,h] = exp(A[h] * softplus(v_flat @ Wdt)); one wave per (b,s)
// ---------------------------------------------------------------------------
__global__ __launch_bounds__(64) void dyn_kernel(const u16* __restrict__ Vb, const float* __restrict__ Wdt,
                                                 const float* __restrict__ Af, float* __restrict__ dynb)
{
  int pos  = blockIdx.x;
  int lane = threadIdx.x;
  float acc[8];
  #pragma unroll
  for (int h = 0; h < 8; ++h) acc[h] = 0.f;
  for (int j = lane; j < 512; j += 64) {
    float v = bf2f(Vb[(size_t)pos * 512 + j]);
    float4 w0 = *(const float4*)(Wdt + j * 8);
    float4 w1 = *(const float4*)(Wdt + j * 8 + 4);
    acc[0] += v * w0.x; acc[1] += v * w0.y; acc[2] += v * w0.z; acc[3] += v * w0.w;
    acc[4] += v * w1.x; acc[5] += v * w1.y; acc[6] += v * w1.z; acc[7] += v * w1.w;
  }
  #pragma unroll
  for (int off = 32; off > 0; off >>= 1)
    #pragma unroll
    for (int h = 0; h < 8; ++h) acc[h] += __shfl_down(acc[h], off, 64);
  if (lane == 0) {
    #pragma unroll
    for (int h = 0; h < 8; ++h) {
      float dt = acc[h];
      float sp = (dt > 20.f) ? dt : log1pf(__expf(dt));
      dynb[(size_t)pos * 8 + h] = __expf(Af[h] * sp);
    }
  }
}

// ---------------------------------------------------------------------------
// V transpose: Vb [b*2048+s][kvh*128+d] -> VTg [((b*4+kvh)*128+d)*2048 + s]
// LDS-tiled, coalesced both directions. grid (32, 4, 2).
// ---------------------------------------------------------------------------
__global__ __launch_bounds__(256) void vtrans_kernel(const u16* __restrict__ Vb, u16* __restrict__ VTg)
{
  const int sx = blockIdx.x, kvh = blockIdx.y, b = blockIdx.z;
  __shared__ __align__(16) u16 T[64][132];
  const int t = threadIdx.x;
  {
    const int r = t >> 2, c = (t & 3) * 32;
    const u16* src = Vb + (size_t)(b * S_LEN + sx * 64 + r) * 512 + kvh * 128 + c;
    #pragma unroll
    for (int i = 0; i < 4; ++i)
      *(uint4*)&T[r][c + i * 8] = *(const uint4*)(src + i * 8);
  }
  __syncthreads();
  {
    const int d = t >> 1, cs = (t & 1) * 32;
    u16* dst = VTg + ((size_t)((b * 4 + kvh) * 128 + d)) * S_LEN + sx * 64 + cs;
    #pragma unroll
    for (int i = 0; i < 4; ++i) {
      u16 tmp[8];
      #pragma unroll
      for (int j = 0; j < 8; ++j) tmp[j] = T[cs + i * 8 + j][d];
      *(uint4*)(dst + i * 8) = *(uint4*)tmp;
    }
  }
}

// ---------------------------------------------------------------------------
// MFMA flash attention with per-key bias dyn[b,k,h]. Block = (b, h, 64-q tile),
// 4 waves x 16 q-rows. QK^T and PV on mfma_f32_16x16x32_bf16; P goes through
// LDS as bf16 (C-layout -> A-layout transform); V^T pre-transposed in ws.
// m/l/alpha state stays in registers (QK-acc and PV-acc rows are lane-aligned).
// ctx aliases Qb (block writes exactly the region it staged).
// ---------------------------------------------------------------------------
__global__ __launch_bounds__(256) void attn_mfma(const u16* __restrict__ Qb, const u16* __restrict__ Kb,
                                                 const u16* __restrict__ VTg, const float* __restrict__ dynb,
                                                 u16* __restrict__ ctx)
{
  const int qblk = (int)gridDim.x - 1 - (int)blockIdx.x;  // heavy blocks first
  const int h = blockIdx.y, b = blockIdx.z, kvh = h >> 1;
  const int q0 = qblk * 64;

  __shared__ __align__(16) u16 Qs[64][132];   // [q][d]
  __shared__ __align__(16) u16 Ks[64][132];   // [key][d]
  __shared__ __align__(16) u16 VTs[128][68];  // [d][key]
  __shared__ __align__(16) u16 Ps[64][68];    // [q][key] bf16 P (per-wave strips)
  __shared__ float dynS[64];

  const int t = threadIdx.x;
  const int w = t >> 6, lane = t & 63, quad = lane >> 4, l16 = lane & 15;

  {  // stage Q tile
    const int r = t >> 2, c = (t & 3) * 32;
    const u16* src = Qb + (size_t)(b * S_LEN + q0 + r) * 1024 + h * 128 + c;
    #pragma unroll
    for (int i = 0; i < 4; ++i)
      *(uint4*)&Qs[r][c + i * 8] = *(const uint4*)(src + i * 8);
  }

  f32x4 accO[8];
  #pragma unroll
  for (int nt = 0; nt < 8; ++nt) accO[nt] = zero4();
  float m_run[4], l_run[4];
  #pragma unroll
  for (int r = 0; r < 4; ++r) { m_run[r] = NEGBIG; l_run[r] = 0.f; }

  for (int kt = 0; kt <= qblk; ++kt) {
    const int k0 = kt * 64;
    __syncthreads();  // prior QK/PV reads of Ks/VTs done
    {  // stage K tile
      const int r = t >> 2, c = (t & 3) * 32;
      const u16* src = Kb + (size_t)(b * S_LEN + k0 + r) * 512 + kvh * 128 + c;
      #pragma unroll
      for (int i = 0; i < 4; ++i)
        *(uint4*)&Ks[r][c + i * 8] = *(const uint4*)(src + i * 8);
    }
    {  // stage V^T tile
      const int d = t >> 1, c = (t & 1) * 32;
      const u16* src = VTg + ((size_t)((b * 4 + kvh) * 128 + d)) * S_LEN + k0 + c;
      #pragma unroll
      for (int i = 0; i < 4; ++i)
        *(uint4*)&VTs[d][c + i * 8] = *(const uint4*)(src + i * 8);
    }
    if (t < 64) dynS[t] = dynb[(size_t)(b * S_LEN + k0 + t) * 8 + h];
    __syncthreads();

    // ---- QK^T: wave strip 16q x 64key ----
    f32x4 accS[4];
    #pragma unroll
    for (int nt = 0; nt < 4; ++nt) accS[nt] = zero4();
    #pragma unroll
    for (int ks = 0; ks < 4; ++ks) {
      bf16x8 a = frag8(&Qs[w * 16 + l16][ks * 32 + quad * 8]);
      #pragma unroll
      for (int nt = 0; nt < 4; ++nt) {
        bf16x8 bk = frag8(&Ks[nt * 16 + l16][ks * 32 + quad * 8]);
        accS[nt] = __builtin_amdgcn_mfma_f32_16x16x32_bf16(a, bk, accS[nt], 0, 0, 0);
      }
    }

    // ---- online softmax on C-layout frags (row = quad*4+r, col = nt*16+l16) ----
    float dv[4];
    #pragma unroll
    for (int nt = 0; nt < 4; ++nt) dv[nt] = dynS[nt * 16 + l16];
    float sc[4][4], mx[4];
    #pragma unroll
    for (int r = 0; r < 4; ++r) mx[r] = NEGBIG;
    #pragma unroll
    for (int nt = 0; nt < 4; ++nt) {
      const int kk = k0 + nt * 16 + l16;
      #pragma unroll
      for (int r = 0; r < 4; ++r) {
        const int qq = q0 + w * 16 + quad * 4 + r;
        float v = accS[nt][r] * SCALE + dv[nt];
        if (kk > qq) v = NEGBIG;
        sc[nt][r] = v;
        mx[r] = fmaxf(mx[r], v);
      }
    }
    #pragma unroll
    for (int off = 1; off < 16; off <<= 1)
      #pragma unroll
      for (int r = 0; r < 4; ++r) mx[r] = fmaxf(mx[r], __shfl_xor(mx[r], off, 64));
    float al[4], sum[4];
    #pragma unroll
    for (int r = 0; r < 4; ++r) {
      const float mn = fmaxf(m_run[r], mx[r]);
      al[r] = __expf(m_run[r] - mn);   // first tile: exp(-huge)=0
      m_run[r] = mn;
      sum[r] = 0.f;
    }
    #pragma unroll
    for (int nt = 0; nt < 4; ++nt)
      #pragma unroll
      for (int r = 0; r < 4; ++r) {
        float p = __expf(sc[nt][r] - m_run[r]);  // masked -> 0
        Ps[w * 16 + quad * 4 + r][nt * 16 + l16] = f2b(p);
        sum[r] += p;
      }
    #pragma unroll
    for (int off = 1; off < 16; off <<= 1)
      #pragma unroll
      for (int r = 0; r < 4; ++r) sum[r] += __shfl_xor(sum[r], off, 64);
    #pragma unroll
    for (int r = 0; r < 4; ++r) l_run[r] = l_run[r] * al[r] + sum[r];

    // ---- rescale O, then PV (P rows are wave-local; in-wave LDS ordering) ----
    #pragma unroll
    for (int nt = 0; nt < 8; ++nt)
      #pragma unroll
      for (int r = 0; r < 4; ++r) accO[nt][r] *= al[r];
    #pragma unroll
    for (int ks = 0; ks < 2; ++ks) {
      bf16x8 a = frag8(&Ps[w * 16 + l16][ks * 32 + quad * 8]);
      #pragma unroll
      for (int nt = 0; nt < 8; ++nt) {
        bf16x8 bv = frag8(&VTs[nt * 16 + l16][ks * 32 + quad * 8]);
        accO[nt] = __builtin_amdgcn_mfma_f32_16x16x32_bf16(a, bv, accO[nt], 0, 0, 0);
      }
    }
  }

  float linv[4];
  #pragma unroll
  for (int r = 0; r < 4; ++r) linv[r] = 1.f / l_run[r];
  #pragma unroll
  for (int nt = 0; nt < 8; ++nt)
    #pragma unroll
    for (int r = 0; r < 4; ++r) {
      const int qq = q0 + w * 16 + quad * 4 + r;
      const int d  = nt * 16 + l16;
      ctx[(size_t)(b * S_LEN + qq) * 1024 + h * 128 + d] = f2b(accO[nt][r] * linv[r]);
    }
}

// ---------------------------------------------------------------------------
extern "C" void kernel_launch(void* const* d_in, const int* in_sizes, int n_in,
                              void* d_out, int out_size, void* d_ws, size_t ws_size,
                              hipStream_t stream)
{
  const float* hidden = (const float*)d_in[0];
  const float* Wq     = (const float*)d_in[1];
  const float* Wk     = (const float*)d_in[2];
  const float* Wv     = (const float*)d_in[3];
  const float* Wdt    = (const float*)d_in[4];
  const float* Af     = (const float*)d_in[5];
  const float* Wo     = (const float*)d_in[6];
  const float* cosb   = (const float*)d_in[7];
  const float* sinb   = (const float*)d_in[8];
  // d_in[9] = causal mask, structurally k>q — not read.
  float* out = (float*)d_out;

  u16* Qb  = (u16*)d_ws;                        // [4096,1024] bf16 (later: ctx)
  u16* Kb  = Qb + (size_t)4096 * 1024;          // [4096, 512] bf16
  u16* Vb  = Kb + (size_t)4096 * 512;           // [4096, 512] bf16
  u16* VTg = Vb + (size_t)4096 * 512;           // [2,4,128,2048] bf16 (V^T)
  float* dynb = (float*)(VTg + (size_t)4096 * 512);  // [4096,8] f32
  u16* ctx = Qb;

  gemm_mfma<float, u16><<<dim3(32, 64), 256, 0, stream>>>(hidden, 1024, 1024,
      Wq, 1024, Qb, 1024,
      Wk,  512, Kb,  512,
      Wv,  512, Vb,  512,
      1024, 1536);
  rope_kernel<<<12288, 256, 0, stream>>>(Qb, Kb, cosb, sinb);
  dyn_kernel<<<4096, 64, 0, stream>>>(Vb, Wdt, Af, dynb);
  vtrans_kernel<<<dim3(32, 4, 2), 256, 0, stream>>>(Vb, VTg);
  attn_mfma<<<dim3(32, 8, 2), 256, 0, stream>>>(Qb, Kb, VTg, dynb, ctx);
  gemm_mfma<u16, float><<<dim3(16, 64), 256, 0, stream>>>(ctx, 1024, 1024,
      Wo, 1024, out, 1024,
      Wo, 1024, out, 1024,
      Wo, 1024, out, 1024,
      1 << 30, 1 << 30);
}

// Round 5
// 438.401 us; speedup vs baseline: 2.8974x; 1.2437x over previous
//
#include <hip/hip_runtime.h>

typedef unsigned short u16;
typedef unsigned int   u32;
typedef __bf16 bf16;
typedef bf16  bf16x8 __attribute__((ext_vector_type(8)));
typedef float f32x4  __attribute__((ext_vector_type(4)));

#define S_LEN 2048
#define SCALE 0.08838834764831845f
#define NEGBIG (-1e30f)

__device__ __forceinline__ float bf2f(u16 u) {
  union { u32 i; float f; } v; v.i = ((u32)u) << 16; return v.f;
}
__device__ __forceinline__ u16 f2b(float f) {
  union { float f; u32 i; } v; v.f = f;
  u32 x = v.i;
  u32 r = x + 0x7fffu + ((x >> 16) & 1u);
  return (u16)(r >> 16);
}

// load 16 consecutive elements as bf16 u16 (convert when f32 source)
__device__ __forceinline__ void load16(const float* p, u16* dst) {
  #pragma unroll
  for (int i = 0; i < 16; i += 4) {
    float4 v = *(const float4*)(p + i);
    dst[i]     = f2b(v.x); dst[i + 1] = f2b(v.y);
    dst[i + 2] = f2b(v.z); dst[i + 3] = f2b(v.w);
  }
}
__device__ __forceinline__ void load16(const u16* p, u16* dst) {
  uint4 v0 = *(const uint4*)p, v1 = *(const uint4*)(p + 8);
  *(uint4*)dst = v0; *(uint4*)(dst + 8) = v1;
}

__device__ __forceinline__ void storeo(float* p, float v) { *p = v; }
__device__ __forceinline__ void storeo(u16* p, float v)   { *p = f2b(v); }

__device__ __forceinline__ bf16x8 frag8(const u16* p) {
  union { uint4 u; bf16x8 v; } c;
  c.u = *(const uint4*)p;
  return c.v;
}
__device__ __forceinline__ bf16x8 frag8u(uint4 u) {
  union { uint4 u; bf16x8 v; } c;
  c.u = u;
  return c.v;
}
__device__ __forceinline__ f32x4 zero4() {
  f32x4 z = {0.f, 0.f, 0.f, 0.f}; return z;
}

// ---------------------------------------------------------------------------
// MFMA GEMM: C[M,N] = A[M,K] * W[K,N]. A f32-or-bf16, W f32 (converted during
// staging), out f32-or-bf16. 64x64 tile, 4 waves x (16m x 64n), BK=64.
// Column routing gives fused Q|K|V in one launch. (unchanged from round 4)
// ---------------------------------------------------------------------------
template <typename TA, typename TO>
__global__ __launch_bounds__(256) void gemm_mfma(
    const TA* __restrict__ A, int lda, int Kdim,
    const float* __restrict__ W0, int ldw0, TO* __restrict__ O0, int ldo0,
    const float* __restrict__ W1, int ldw1, TO* __restrict__ O1, int ldo1,
    const float* __restrict__ W2, int ldw2, TO* __restrict__ O2, int ldo2,
    int c1, int c2)
{
  const int n0 = blockIdx.x * 64;
  const int m0 = blockIdx.y * 64;
  const float* W; TO* O; int ldw, ldo, col;
  if (n0 < c1)      { W = W0; O = O0; ldw = ldw0; ldo = ldo0; col = n0; }
  else if (n0 < c2) { W = W1; O = O1; ldw = ldw1; ldo = ldo1; col = n0 - c1; }
  else              { W = W2; O = O2; ldw = ldw2; ldo = ldo2; col = n0 - c2; }

  __shared__ __align__(16) u16 As[64][72];   // [m][k]
  __shared__ __align__(16) u16 Bs[64][72];   // [n][k]  (W transposed)

  const int t    = threadIdx.x;
  const int w    = t >> 6, lane = t & 63, quad = lane >> 4, l16 = lane & 15;
  const int sr   = t >> 2, scc = (t & 3) * 16;

  f32x4 acc[4];
  #pragma unroll
  for (int nt = 0; nt < 4; ++nt) acc[nt] = zero4();

  for (int k0 = 0; k0 < Kdim; k0 += 64) {
    __syncthreads();
    {
      u16 tmp[16];
      load16(A + (size_t)(m0 + sr) * lda + k0 + scc, tmp);
      *(uint4*)&As[sr][scc]     = *(uint4*)tmp;
      *(uint4*)&As[sr][scc + 8] = *(uint4*)(tmp + 8);
    }
    {
      const float* wp = W + (size_t)(k0 + sr) * ldw + col + scc;
      #pragma unroll
      for (int i = 0; i < 16; i += 4) {
        float4 v = *(const float4*)(wp + i);
        Bs[scc + i][sr]     = f2b(v.x);
        Bs[scc + i + 1][sr] = f2b(v.y);
        Bs[scc + i + 2][sr] = f2b(v.z);
        Bs[scc + i + 3][sr] = f2b(v.w);
      }
    }
    __syncthreads();
    #pragma unroll
    for (int ks = 0; ks < 2; ++ks) {
      bf16x8 a = frag8(&As[w * 16 + l16][ks * 32 + quad * 8]);
      #pragma unroll
      for (int nt = 0; nt < 4; ++nt) {
        bf16x8 bw = frag8(&Bs[nt * 16 + l16][ks * 32 + quad * 8]);
        acc[nt] = __builtin_amdgcn_mfma_f32_16x16x32_bf16(a, bw, acc[nt], 0, 0, 0);
      }
    }
  }
  #pragma unroll
  for (int nt = 0; nt < 4; ++nt)
    #pragma unroll
    for (int r = 0; r < 4; ++r) {
      const int m = m0 + w * 16 + quad * 4 + r;
      const int n = col + nt * 16 + l16;
      storeo(O + (size_t)m * ldo + n, acc[nt][r]);
    }
}

// ---------------------------------------------------------------------------
// RoPE in place on Q [4096,8,128] and K [4096,4,128] (bf16 ws).
// ---------------------------------------------------------------------------
__global__ __launch_bounds__(256) void rope_kernel(u16* __restrict__ Qb, u16* __restrict__ Kb,
                                                   const float* __restrict__ cb, const float* __restrict__ sb)
{
  int idx = blockIdx.x * 256 + threadIdx.x;
  int d    = idx & 63;
  int head = (idx >> 6) % 12;
  int pos  = idx / (64 * 12);
  int s    = pos & (S_LEN - 1);
  float c0 = cb[s * 128 + d];
  float s0 = sb[s * 128 + d];
  float c1 = cb[s * 128 + d + 64];
  float s1 = sb[s * 128 + d + 64];
  u16* base = (head < 8) ? (Qb + (size_t)pos * 1024 + head * 128)
                         : (Kb + (size_t)pos * 512 + (head - 8) * 128);
  float x0 = bf2f(base[d]), x1 = bf2f(base[d + 64]);
  base[d]      = f2b(x0 * c0 - x1 * s0);
  base[d + 64] = f2b(x1 * c1 + x0 * s1);
}

// ---------------------------------------------------------------------------
// dyn[b,s,h] = exp(A[h] * softplus(v_flat @ Wdt)); one wave per (b,s)
// ---------------------------------------------------------------------------
__global__ __launch_bounds__(64) void dyn_kernel(const u16* __restrict__ Vb, const float* __restrict__ Wdt,
                                                 const float* __restrict__ Af, float* __restrict__ dynb)
{
  int pos  = blockIdx.x;
  int lane = threadIdx.x;
  float acc[8];
  #pragma unroll
  for (int h = 0; h < 8; ++h) acc[h] = 0.f;
  for (int j = lane; j < 512; j += 64) {
    float v = bf2f(Vb[(size_t)pos * 512 + j]);
    float4 w0 = *(const float4*)(Wdt + j * 8);
    float4 w1 = *(const float4*)(Wdt + j * 8 + 4);
    acc[0] += v * w0.x; acc[1] += v * w0.y; acc[2] += v * w0.z; acc[3] += v * w0.w;
    acc[4] += v * w1.x; acc[5] += v * w1.y; acc[6] += v * w1.z; acc[7] += v * w1.w;
  }
  #pragma unroll
  for (int off = 32; off > 0; off >>= 1)
    #pragma unroll
    for (int h = 0; h < 8; ++h) acc[h] += __shfl_down(acc[h], off, 64);
  if (lane == 0) {
    #pragma unroll
    for (int h = 0; h < 8; ++h) {
      float dt = acc[h];
      float sp = (dt > 20.f) ? dt : log1pf(__expf(dt));
      dynb[(size_t)pos * 8 + h] = __expf(Af[h] * sp);
    }
  }
}

// ---------------------------------------------------------------------------
// V transpose: Vb [b*2048+s][kvh*128+d] -> VTg [((b*4+kvh)*128+d)*2048 + s]
// ---------------------------------------------------------------------------
__global__ __launch_bounds__(256) void vtrans_kernel(const u16* __restrict__ Vb, u16* __restrict__ VTg)
{
  const int sx = blockIdx.x, kvh = blockIdx.y, b = blockIdx.z;
  __shared__ __align__(16) u16 T[64][132];
  const int t = threadIdx.x;
  {
    const int r = t >> 2, c = (t & 3) * 32;
    const u16* src = Vb + (size_t)(b * S_LEN + sx * 64 + r) * 512 + kvh * 128 + c;
    #pragma unroll
    for (int i = 0; i < 4; ++i)
      *(uint4*)&T[r][c + i * 8] = *(const uint4*)(src + i * 8);
  }
  __syncthreads();
  {
    const int d = t >> 1, cs = (t & 1) * 32;
    u16* dst = VTg + ((size_t)((b * 4 + kvh) * 128 + d)) * S_LEN + sx * 64 + cs;
    #pragma unroll
    for (int i = 0; i < 4; ++i) {
      u16 tmp[8];
      #pragma unroll
      for (int j = 0; j < 8; ++j) tmp[j] = T[cs + i * 8 + j][d];
      *(uint4*)(dst + i * 8) = *(uint4*)tmp;
    }
  }
}

// ---------------------------------------------------------------------------
// MFMA flash attention v3: register-prefetch pipeline + register Q.
// Block = (b, h, 64 q-rows); balanced qblk mapping; 4 waves x 16 q-rows.
// Per k-tile: prefetch next K/VT tile into REGISTERS, compute current tile
// from LDS, barrier, ds_write prefetched regs, barrier. The vmcnt drain at
// the barrier happens ~2000 cycles after load issue -> latency hidden.
// LDS 43.3 KB (no Q tile, single K/V buffer). ctx aliases Qb.
// ---------------------------------------------------------------------------
__global__ __launch_bounds__(256) void attn_mfma(const u16* __restrict__ Qb, const u16* __restrict__ Kb,
                                                 const u16* __restrict__ VTg, const float* __restrict__ dynb,
                                                 u16* __restrict__ ctx)
{
  // balanced mapping: adjacent blocks AND stride-256 blocks pair to 33 tiles
  const int x = blockIdx.x, h = blockIdx.y, b = blockIdx.z;
  int qblk = (x & 1) ? (31 - (x >> 1)) : (x >> 1);
  if (b) qblk = 31 - qblk;
  const int kvh = h >> 1;
  const int q0 = qblk * 64;

  __shared__ __align__(16) u16 Ks[64][132];   // [key][d]
  __shared__ __align__(16) u16 VTs[128][68];  // [d][key]
  __shared__ __align__(16) u16 Ps[64][68];    // [q][key] bf16 P (wave strips)
  __shared__ float dynS[64];

  const int t = threadIdx.x;
  const int w = t >> 6, lane = t & 63, quad = lane >> 4, l16 = lane & 15;
  const int lr = t >> 2, lc = (t & 3) * 32;   // K staging: 4 lanes/row
  const int vd = t >> 1, vc = (t & 1) * 32;   // VT staging: 2 lanes/row

  // Q fragments in registers (A-layout: m=l16, k=ks*32+quad*8+j)
  bf16x8 qf[4];
  {
    const u16* qrow = Qb + (size_t)(b * S_LEN + q0 + w * 16 + l16) * 1024 + h * 128 + quad * 8;
    #pragma unroll
    for (int ks = 0; ks < 4; ++ks) qf[ks] = frag8(qrow + ks * 32);
  }

  const u16* Kbase = Kb + (size_t)(b * S_LEN) * 512 + kvh * 128;
  const u16* Vbase = VTg + ((size_t)((b * 4 + kvh) * 128 + vd)) * S_LEN;

  uint4 kr[4], vr[4]; float dyp = 0.f;
  {  // prologue: load tile 0, write to LDS
    const u16* src = Kbase + (size_t)lr * 512 + lc;
    #pragma unroll
    for (int i = 0; i < 4; ++i) kr[i] = *(const uint4*)(src + i * 8);
    const u16* vs = Vbase + vc;
    #pragma unroll
    for (int i = 0; i < 4; ++i) vr[i] = *(const uint4*)(vs + i * 8);
    if (t < 64) dyp = dynb[(size_t)(b * S_LEN + t) * 8 + h];
    #pragma unroll
    for (int i = 0; i < 4; ++i) *(uint4*)&Ks[lr][lc + i * 8] = kr[i];
    #pragma unroll
    for (int i = 0; i < 4; ++i) *(uint4*)&VTs[vd][vc + i * 8] = vr[i];
    if (t < 64) dynS[t] = dyp;
  }
  __syncthreads();

  f32x4 accO[8];
  #pragma unroll
  for (int nt = 0; nt < 8; ++nt) accO[nt] = zero4();
  float m_run[4], l_run[4];
  #pragma unroll
  for (int r = 0; r < 4; ++r) { m_run[r] = NEGBIG; l_run[r] = 0.f; }

  for (int kt = 0; kt <= qblk; ++kt) {
    const int k0 = kt * 64;
    // ---- prefetch tile kt+1 into registers (in flight during compute) ----
    if (kt < qblk) {
      const int k0n = k0 + 64;
      const u16* src = Kbase + (size_t)(k0n + lr) * 512 + lc;
      #pragma unroll
      for (int i = 0; i < 4; ++i) kr[i] = *(const uint4*)(src + i * 8);
      const u16* vs = Vbase + k0n + vc;
      #pragma unroll
      for (int i = 0; i < 4; ++i) vr[i] = *(const uint4*)(vs + i * 8);
      if (t < 64) dyp = dynb[(size_t)(b * S_LEN + k0n + t) * 8 + h];
    }

    // ---- QK^T: wave strip 16q x 64key ----
    f32x4 accS[4];
    #pragma unroll
    for (int nt = 0; nt < 4; ++nt) accS[nt] = zero4();
    #pragma unroll
    for (int ks = 0; ks < 4; ++ks) {
      #pragma unroll
      for (int nt = 0; nt < 4; ++nt) {
        bf16x8 bk = frag8(&Ks[nt * 16 + l16][ks * 32 + quad * 8]);
        accS[nt] = __builtin_amdgcn_mfma_f32_16x16x32_bf16(qf[ks], bk, accS[nt], 0, 0, 0);
      }
    }

    // ---- online softmax (C-layout: row=quad*4+r, col=nt*16+l16) ----
    float dv[4];
    #pragma unroll
    for (int nt = 0; nt < 4; ++nt) dv[nt] = dynS[nt * 16 + l16];
    float sc[4][4], mx[4];
    #pragma unroll
    for (int r = 0; r < 4; ++r) mx[r] = NEGBIG;
    #pragma unroll
    for (int nt = 0; nt < 4; ++nt) {
      const int kk = k0 + nt * 16 + l16;
      #pragma unroll
      for (int r = 0; r < 4; ++r) {
        const int qq = q0 + w * 16 + quad * 4 + r;
        float v = accS[nt][r] * SCALE + dv[nt];
        if (kk > qq) v = NEGBIG;
        sc[nt][r] = v;
        mx[r] = fmaxf(mx[r], v);
      }
    }
    #pragma unroll
    for (int off = 1; off < 16; off <<= 1)
      #pragma unroll
      for (int r = 0; r < 4; ++r) mx[r] = fmaxf(mx[r], __shfl_xor(mx[r], off, 64));
    float al[4], sum[4];
    #pragma unroll
    for (int r = 0; r < 4; ++r) {
      const float mn = fmaxf(m_run[r], mx[r]);
      al[r] = __expf(m_run[r] - mn);   // first tile: exp(-huge)=0
      m_run[r] = mn;
      sum[r] = 0.f;
    }
    #pragma unroll
    for (int nt = 0; nt < 4; ++nt)
      #pragma unroll
      for (int r = 0; r < 4; ++r) {
        float p = __expf(sc[nt][r] - m_run[r]);  // masked -> 0
        Ps[w * 16 + quad * 4 + r][nt * 16 + l16] = f2b(p);
        sum[r] += p;
      }
    #pragma unroll
    for (int off = 1; off < 16; off <<= 1)
      #pragma unroll
      for (int r = 0; r < 4; ++r) sum[r] += __shfl_xor(sum[r], off, 64);
    #pragma unroll
    for (int r = 0; r < 4; ++r) l_run[r] = l_run[r] * al[r] + sum[r];

    // ---- rescale O, then PV (P rows wave-local; in-wave LDS ordering) ----
    #pragma unroll
    for (int nt = 0; nt < 8; ++nt)
      #pragma unroll
      for (int r = 0; r < 4; ++r) accO[nt][r] *= al[r];
    #pragma unroll
    for (int ks = 0; ks < 2; ++ks) {
      bf16x8 a = frag8(&Ps[w * 16 + l16][ks * 32 + quad * 8]);
      #pragma unroll
      for (int nt = 0; nt < 8; ++nt) {
        bf16x8 bv = frag8(&VTs[nt * 16 + l16][ks * 32 + quad * 8]);
        accO[nt] = __builtin_amdgcn_mfma_f32_16x16x32_bf16(a, bv, accO[nt], 0, 0, 0);
      }
    }

    // ---- commit prefetched tile to LDS ----
    __syncthreads();   // all waves done reading Ks/VTs/dynS for tile kt
    if (kt < qblk) {
      #pragma unroll
      for (int i = 0; i < 4; ++i) *(uint4*)&Ks[lr][lc + i * 8] = kr[i];
      #pragma unroll
      for (int i = 0; i < 4; ++i) *(uint4*)&VTs[vd][vc + i * 8] = vr[i];
      if (t < 64) dynS[t] = dyp;
      __syncthreads();
    }
  }

  float linv[4];
  #pragma unroll
  for (int r = 0; r < 4; ++r) linv[r] = 1.f / l_run[r];
  #pragma unroll
  for (int nt = 0; nt < 8; ++nt)
    #pragma unroll
    for (int r = 0; r < 4; ++r) {
      const int qq = q0 + w * 16 + quad * 4 + r;
      const int d  = nt * 16 + l16;
      ctx[(size_t)(b * S_LEN + qq) * 1024 + h * 128 + d] = f2b(accO[nt][r] * linv[r]);
    }
}

// ---------------------------------------------------------------------------
extern "C" void kernel_launch(void* const* d_in, const int* in_sizes, int n_in,
                              void* d_out, int out_size, void* d_ws, size_t ws_size,
                              hipStream_t stream)
{
  const float* hidden = (const float*)d_in[0];
  const float* Wq     = (const float*)d_in[1];
  const float* Wk     = (const float*)d_in[2];
  const float* Wv     = (const float*)d_in[3];
  const float* Wdt    = (const float*)d_in[4];
  const float* Af     = (const float*)d_in[5];
  const float* Wo     = (const float*)d_in[6];
  const float* cosb   = (const float*)d_in[7];
  const float* sinb   = (const float*)d_in[8];
  // d_in[9] = causal mask, structurally k>q — not read.
  float* out = (float*)d_out;

  u16* Qb  = (u16*)d_ws;                        // [4096,1024] bf16 (later: ctx)
  u16* Kb  = Qb + (size_t)4096 * 1024;          // [4096, 512] bf16
  u16* Vb  = Kb + (size_t)4096 * 512;           // [4096, 512] bf16
  u16* VTg = Vb + (size_t)4096 * 512;           // [2,4,128,2048] bf16 (V^T)
  float* dynb = (float*)(VTg + (size_t)4096 * 512);  // [4096,8] f32
  u16* ctx = Qb;

  gemm_mfma<float, u16><<<dim3(32, 64), 256, 0, stream>>>(hidden, 1024, 1024,
      Wq, 1024, Qb, 1024,
      Wk,  512, Kb,  512,
      Wv,  512, Vb,  512,
      1024, 1536);
  rope_kernel<<<12288, 256, 0, stream>>>(Qb, Kb, cosb, sinb);
  dyn_kernel<<<4096, 64, 0, stream>>>(Vb, Wdt, Af, dynb);
  vtrans_kernel<<<dim3(32, 4, 2), 256, 0, stream>>>(Vb, VTg);
  attn_mfma<<<dim3(32, 8, 2), 256, 0, stream>>>(Qb, Kb, VTg, dynb, ctx);
  gemm_mfma<u16, float><<<dim3(16, 64), 256, 0, stream>>>(ctx, 1024, 1024,
      Wo, 1024, out, 1024,
      Wo, 1024, out, 1024,
      Wo, 1024, out, 1024,
      1 << 30, 1 << 30);
}